// Round 18
// baseline (88.918 us; speedup 1.0000x reference)
//
#include <hip/hip_runtime.h>
#include <hip/hip_bf16.h>
#include <cstddef>

#define NE 65536
#define ND 256
#define NP 8
#define RBLK 64              // hist/scatter blocks
#define EPB (NE / RBLK)      // 1024 edges per routing block
#define TR 32                // rows per main tile
#define MAXT 2056            // max tiles: 2048 + 8

typedef short bf16x8 __attribute__((ext_vector_type(8)));
typedef float f32x4  __attribute__((ext_vector_type(4)));
typedef const __attribute__((address_space(1))) unsigned int* gas_t;
typedef __attribute__((address_space(3))) unsigned int* las_t;

__device__ __forceinline__ unsigned short f2bf(float f) {
  unsigned int u = __float_as_uint(f);
  u += 0x7FFFu + ((u >> 16) & 1u);   // round-to-nearest-even
  return (unsigned short)(u >> 16);
}
__device__ __forceinline__ int load_idx(const void* idxraw, int is32, int e) {
  return is32 ? ((const int*)idxraw)[e] : (int)((const long long*)idxraw)[e];
}
// idx dtype sniff: odd 32-bit words all-zero <=> int64 (values < 8)
__device__ __forceinline__ int sniff_is32(const void* idxraw, int* lflag, int bsel) {
  int tid = threadIdx.x;
  if (tid == 0) *lflag = 0;
  __syncthreads();
  const unsigned int* w = (const unsigned int*)idxraw;
  unsigned int val = w[((bsel & 63) * 256 + tid) * 2 + 1];
  if (__any(val != 0) && (tid & 63) == 0) atomicOr(lflag, 1);
  __syncthreads();
  return *lflag;
}

// ---- fused prep (W_bil frag + v) and per-block histogram (R12/R17 verbatim) ----
__global__ __launch_bounds__(256) void k_pre0(const float* __restrict__ Wbil,
                                              const float* __restrict__ blr,
                                              const void* __restrict__ idxraw,
                                              unsigned short* __restrict__ WbT,
                                              float* __restrict__ v,
                                              int* __restrict__ counts) {
  int b = blockIdx.x, t = threadIdx.x;
  if (b < 32) {
    int s = b * 256 + t;
    int kt = s >> 10, c = (s >> 6) & 15, l = s & 63;
    int col = c * 16 + (l & 15);
    int k0 = kt * 32 + (l >> 4) * 8;
    union { uint4 u; unsigned short h[8]; } uu;
#pragma unroll
    for (int j = 0; j < 8; ++j)
      uu.h[j] = f2bf(Wbil[(k0 + j) * ND + col]);
    *(uint4*)(WbT + (size_t)s * 8) = uu.u;
  } else if (b < 40) {
    int p = b - 32;
    float s = 0.f;
    for (int k = 0; k < ND; ++k)
      s = fmaf(blr[p * ND + k], Wbil[k * ND + t], s);
    v[p * ND + t] = s;
  } else {
    __shared__ int h[NP];
    __shared__ int lflag;
    int hb = b - 40;
    int is32 = sniff_is32(idxraw, &lflag, hb);
    if (t < NP) h[t] = 0;
    __syncthreads();
    int base = hb * EPB;
#pragma unroll
    for (int i = 0; i < EPB / 256; ++i) {
      int p = load_idx(idxraw, is32, base + t + i * 256);
      atomicAdd(&h[p], 1);
    }
    __syncthreads();
    if (t < NP) counts[hb * NP + t] = h[t];
  }
}

// ---- scan: totals, CSR offsets, 32-row tile prefix, per-block bases ----
__global__ __launch_bounds__(64) void k_scan(const int* __restrict__ counts,
                                             int* __restrict__ hdr,
                                             int* __restrict__ bases) {
  __shared__ int cnt[NP];
  __shared__ int off[NP + 1];
  int q = threadIdx.x;
  if (q < NP) {
    int s = 0;
    for (int b = 0; b < RBLK; ++b) s += counts[b * NP + q];
    cnt[q] = s;
  }
  __syncthreads();
  if (q == 0) {
    int o = 0, tt = 0;
    for (int p = 0; p < NP; ++p) {
      off[p] = o; hdr[p] = o; hdr[9 + p] = tt;
      o += cnt[p];
      tt += (cnt[p] + TR - 1) / TR;
    }
    off[NP] = o; hdr[NP] = o; hdr[9 + NP] = tt;
  }
  __syncthreads();
  if (q < NP) {
    int run = off[q];
    for (int b = 0; b < RBLK; ++b) {
      bases[b * NP + q] = run;
      run += counts[b * NP + q];
    }
  }
}

// ---- fused CSR scatter + C_p precompute (R12/R17 verbatim) ----
__global__ __launch_bounds__(256) void k_sc2(const void* __restrict__ idxraw,
                                             const int* __restrict__ bases,
                                             int* __restrict__ perm,
                                             const float* __restrict__ Wlr,
                                             const unsigned short* __restrict__ WbT,
                                             unsigned short* __restrict__ Cst) {
  __shared__ unsigned short aF[2048 * 8];   // used by cpre half only
  int b = blockIdx.x, tid = threadIdx.x;
  if (b < 64) {
    __shared__ int cur[NP];
    __shared__ int lflag;
    int is32 = sniff_is32(idxraw, &lflag, b);
    if (tid < NP) cur[tid] = bases[b * NP + tid];
    __syncthreads();
    int base = b * EPB;
#pragma unroll
    for (int i = 0; i < EPB / 256; ++i) {
      int e = base + tid + i * 256;
      int p = load_idx(idxraw, is32, e);
      int slot = atomicAdd(&cur[p], 1);
      perm[slot] = e;
    }
    return;
  }
  int blk = b - 64;
  int p = blk >> 2;
  int i0 = (blk & 3) * 64;
  const float* Wp = Wlr + (size_t)p * ND * ND;
#pragma unroll
  for (int it = 0; it < 8; ++it) {
    int s = tid + it * 256;
    int kt = s >> 8, r = (s >> 6) & 3, l = s & 63;
    int i = r * 16 + (l & 15);
    int k0 = kt * 32 + (l >> 4) * 8;
    union { uint4 u; unsigned short h[8]; } uu;
#pragma unroll
    for (int j = 0; j < 8; ++j)
      uu.h[j] = f2bf(Wp[(size_t)(k0 + j) * ND + i0 + i]);
    *(uint4*)(aF + (size_t)s * 8) = uu.u;
  }
  __syncthreads();
  int w = tid >> 6, l = tid & 63;
  f32x4 zero = {0.f, 0.f, 0.f, 0.f};
  f32x4 acc[16];
#pragma unroll
  for (int c = 0; c < 16; ++c) acc[c] = zero;
  for (int kt = 0; kt < 8; ++kt) {
    bf16x8 a = *(const bf16x8*)(aF + (size_t)((kt * 4 + w) * 64 + l) * 8);
#pragma unroll
    for (int c = 0; c < 16; ++c) {
      bf16x8 bb = *(const bf16x8*)(WbT + (size_t)((kt * 16 + c) * 64 + l) * 8);
      acc[c] = __builtin_amdgcn_mfma_f32_16x16x32_bf16(a, bb, acc[c], 0, 0, 0);
    }
  }
  unsigned short* Cp = Cst + (size_t)p * ND * ND;
#pragma unroll
  for (int c = 0; c < 16; ++c) {
#pragma unroll
    for (int q = 0; q < 4; ++q) {
      int i = i0 + w * 16 + ((l >> 4) * 4) + q;
      int j = c * 16 + (l & 15);
      int pos = ((i >> 5) * 16 + (j >> 4)) * 512 + (((i >> 3) & 3) * 16 + (j & 15)) * 8 + (i & 7);
      Cp[pos] = f2bf(acc[c][q]);
    }
  }
}

// ---- main v18: k_repack's PROVEN 2.3 TB/s read front-end + GEMM back-end. ----
// 2056 blocks x 256 thr (4 waves), one 32-row CSR tile, one 64 KB fp32 slab
// (rows 0-31 zs, 32-63 zd). ALL 64 rows issued as async global_load_lds at
// block entry (16/wave, zero VGPR destinations -> the compiler CANNOT defer
// them, unlike R12/R17 where VGPR throttling serialized staging). 2 blocks/CU:
// block A's 64 KB burst flies under block B's compute. Source addresses
// pre-swizzled (granule XOR row&7) so LDS A-reads/epilogue are bank-spread.
__global__ __launch_bounds__(256, 2) void k_main(const float* __restrict__ zsrc,
                                                 const float* __restrict__ zdst,
                                                 const int* __restrict__ perm,
                                                 const int* __restrict__ hdr,
                                                 const unsigned short* __restrict__ Cst,
                                                 const float* __restrict__ v,
                                                 const float* __restrict__ bbil,
                                                 float* __restrict__ out) {
  __shared__ float slab[64][256];        // 64 KiB
  __shared__ float red[4][TR];           // 512 B
  __shared__ int eids[TR];
  int tid = threadIdx.x;
  int bid = blockIdx.x;
  if (bid >= hdr[9 + NP]) return;
  int p = 0;
#pragma unroll
  for (int q = 1; q < NP; ++q) p += (bid >= hdr[9 + q]) ? 1 : 0;
  int t = bid - hdr[9 + p];
  int cbeg = hdr[p], cend = hdr[p + 1];
  int ebase = cbeg + t * TR;
  int nrow = cend - ebase; if (nrow > TR) nrow = TR;
  if (tid < TR) {
    int r = ebase + tid; if (r > cend - 1) r = cend - 1;
    eids[tid] = perm[r];
  }
  __syncthreads();
  int w = tid >> 6, l = tid & 63;

  // ---- async burst: wave w stages slab rows [w*16, w*16+16) ----
#pragma unroll
  for (int i = 0; i < 16; ++i) {
    int r = w * 16 + i;                  // 0-31: zs rows; 32-63: zd rows
    int er = r & 31;
    const float* g = ((r < 32) ? zsrc : zdst) + (size_t)eids[er] * ND;
    unsigned off = (unsigned)((l ^ (r & 7)) << 2);   // granule-XOR pre-swizzle
    __builtin_amdgcn_global_load_lds((gas_t)(const void*)(g + off),
                                     (las_t)(void*)&slab[r][0], 16, 0, 0);
  }
  __syncthreads();   // drains vmcnt: tile resident

  // ---- GEMM: wave w covers col-tiles {4w..4w+3}; 2 row-strips ----
  const unsigned short* Cp = Cst + (size_t)p * ND * ND;
  f32x4 zero = {0.f, 0.f, 0.f, 0.f};
  f32x4 acc[2][4];
#pragma unroll
  for (int sr = 0; sr < 2; ++sr)
#pragma unroll
    for (int cl = 0; cl < 4; ++cl) acc[sr][cl] = zero;
  int hi = l >> 4, rr = l & 15;
  unsigned sxr = (unsigned)(rr & 7);
#pragma unroll
  for (int kt = 0; kt < 8; ++kt) {
    bf16x8 a[2];
#pragma unroll
    for (int sr = 0; sr < 2; ++sr) {
      const char* rowb = (const char*)&slab[sr * 16 + rr][0];
      unsigned g0 = (unsigned)(kt * 8 + hi * 2);
      float4 f0 = *(const float4*)(rowb + ((g0 ^ sxr) << 4));
      float4 f1 = *(const float4*)(rowb + (((g0 + 1) ^ sxr) << 4));
      union { bf16x8 vv; unsigned short h[8]; } ua;
      ua.h[0] = f2bf(f0.x); ua.h[1] = f2bf(f0.y); ua.h[2] = f2bf(f0.z); ua.h[3] = f2bf(f0.w);
      ua.h[4] = f2bf(f1.x); ua.h[5] = f2bf(f1.y); ua.h[6] = f2bf(f1.z); ua.h[7] = f2bf(f1.w);
      a[sr] = ua.vv;
    }
#pragma unroll
    for (int cl = 0; cl < 4; ++cl) {
      bf16x8 bb = *(const bf16x8*)(Cp + (size_t)((kt * 16 + (w * 4 + cl)) * 64 + l) * 8);
#pragma unroll
      for (int sr = 0; sr < 2; ++sr)
        acc[sr][cl] = __builtin_amdgcn_mfma_f32_16x16x32_bf16(a[sr], bb, acc[sr][cl], 0, 0, 0);
    }
  }

  // ---- fused epilogue: fp32 z_dst from slab rows 32-63; 16-lane reduce ----
  float vloc[4];
#pragma unroll
  for (int cl = 0; cl < 4; ++cl)
    vloc[cl] = v[p * ND + (w * 4 + cl) * 16 + rr];
#pragma unroll
  for (int sr = 0; sr < 2; ++sr) {
#pragma unroll
    for (int q = 0; q < 4; ++q) {
      int row = sr * 16 + hi * 4 + q;        // D-layout: col=l&15, row=(l>>4)*4+reg
      const char* zdb = (const char*)&slab[32 + row][0];
      unsigned sw = (unsigned)(row & 7);
      float sv = 0.f;
#pragma unroll
      for (int cl = 0; cl < 4; ++cl) {
        int col = (w * 4 + cl) * 16 + rr;
        float zv = *(const float*)(zdb + ((((unsigned)(col >> 2) ^ sw) << 4) | ((unsigned)(col & 3) << 2)));
        sv = fmaf(acc[sr][cl][q] + vloc[cl], zv, sv);
      }
      sv += __shfl_xor(sv, 1, 64);
      sv += __shfl_xor(sv, 2, 64);
      sv += __shfl_xor(sv, 4, 64);
      sv += __shfl_xor(sv, 8, 64);
      if (rr == 0) red[w][row] = sv;
    }
  }
  __syncthreads();
  if (tid < TR && tid < nrow) {
    float sc = bbil[0];
#pragma unroll
    for (int ww = 0; ww < 4; ++ww) sc += red[ww][tid];
    out[eids[tid]] = sc;
  }
}

extern "C" void kernel_launch(void* const* d_in, const int* in_sizes, int n_in,
                              void* d_out, int out_size, void* d_ws, size_t ws_size,
                              hipStream_t stream) {
  // setup_inputs() dict order: z_src, z_dst, W_lr, b_lr, W_bil, b_bil, lr_pair_idx
  const float* zsrc = (const float*)d_in[0];
  const float* zdst = (const float*)d_in[1];
  const float* Wlr  = (const float*)d_in[2];
  const float* blr  = (const float*)d_in[3];
  const float* Wbil = (const float*)d_in[4];
  const float* bbil = (const float*)d_in[5];
  const void*  idx  = (const void*)d_in[6];
  float* out = (float*)d_out;

  char* ws = (char*)d_ws;
  int* hdr    = (int*)ws;                                  // 72 B
  int* counts = (int*)(ws + 4096);                         // 2 KiB
  int* bases  = (int*)(ws + 8192);                         // 2 KiB
  int* perm   = (int*)(ws + 16384);                        // 256 KiB (CSR)
  unsigned short* WbT = (unsigned short*)(ws + 16384 + (size_t)NE * 4);            // 128 KiB
  float* v = (float*)(ws + 16384 + (size_t)NE * 4 + 131072);                       // 8 KiB
  unsigned short* Cst = (unsigned short*)(ws + 16384 + (size_t)NE * 4 + 131072 + 8192); // 1 MiB

  k_pre0<<<104, 256, 0, stream>>>(Wbil, blr, idx, WbT, v, counts);
  k_scan<<<1, 64, 0, stream>>>(counts, hdr, bases);
  k_sc2<<<96, 256, 0, stream>>>(idx, bases, perm, Wlr, WbT, Cst);
  k_main<<<MAXT, 256, 0, stream>>>(zsrc, zdst, perm, hdr, Cst, v, bbil, out);
}